// Round 3
// baseline (4965.617 us; speedup 1.0000x reference)
//
#include <hip/hip_runtime.h>
#include <hip/hip_cooperative_groups.h>
#include <cstdint>
#include <cstddef>

namespace cg = cooperative_groups;

#define NNODES 10000
#define HDIM 64
#define INDIM 128
#define TSTEPS 50
#define GBLK 768
#define GWAVES (GBLK*8)   /* 6144 waves, 3 blocks/CU guaranteed by launch_bounds(512,6) */

__device__ __forceinline__ float sigmoidf_(float x){ return 1.0f/(1.0f+__expf(-x)); }
__device__ __forceinline__ float tanhf_(float x){ float e=__expf(2.0f*x); return 1.0f-2.0f/(e+1.0f); }

__device__ __forceinline__ uint32_t pack_bf16x2(float a, float b){
  uint32_t ua = __float_as_uint(a), ub = __float_as_uint(b);
  ua = (ua + 0x7fffu + ((ua>>16)&1u)) >> 16;          // rne
  ub = (ub + 0x7fffu + ((ub>>16)&1u)) >> 16;
  return ua | (ub<<16);
}

__global__ void hist_kernel(const int* __restrict__ src, const int* __restrict__ dst,
                            int* __restrict__ deg_out, int* __restrict__ deg_in, int E){
  int e = blockIdx.x*blockDim.x + threadIdx.x;
  if (e < E){
    atomicAdd(&deg_out[src[e]], 1);
    atomicAdd(&deg_in[dst[e]], 1);
  }
}

// row_off uses degrees PADDED to multiples of 8 (branch-free 8-unroll gather)
__global__ void scan_kernel(const int* __restrict__ deg_in, const int* __restrict__ deg_out,
                            int* __restrict__ row_off, int* __restrict__ cursor,
                            float* __restrict__ norm_s, float* __restrict__ norm_d){
  __shared__ int part[256];
  int tid = threadIdx.x;
  const int CH = (NNODES + 255)/256;   // 40
  int base = tid*CH;
  int local = 0;
  for (int k=0;k<CH;k++){ int n=base+k; if(n<NNODES) local += (deg_in[n]+7)&~7; }
  part[tid]=local;
  __syncthreads();
  if (tid==0){
    int run=0;
    for(int i=0;i<256;i++){ int t=part[i]; part[i]=run; run+=t; }
  }
  __syncthreads();
  int run = part[tid];
  for (int k=0;k<CH;k++){
    int n=base+k;
    if (n<NNODES){
      int di = deg_in[n];
      row_off[n]=run; cursor[n]=run;
      run += (di+7)&~7;
      norm_d[n] = rsqrtf(fmaxf((float)di,1.0f));
      norm_s[n] = rsqrtf(fmaxf((float)deg_out[n],1.0f));
    }
  }
  if (tid==255) row_off[NNODES]=run;   // padded E
}

__global__ void fill_kernel(const int* __restrict__ src, const int* __restrict__ dst,
                            int* __restrict__ cursor, int* __restrict__ csr, int E){
  int e = blockIdx.x*blockDim.x + threadIdx.x;
  if (e<E){
    int pos = atomicAdd(&cursor[dst[e]],1);
    csr[pos] = src[e];
  }
}

__global__ void pad_kernel(const int* __restrict__ row_off, const int* __restrict__ cursor,
                           int* __restrict__ csr){
  int n = blockIdx.x*blockDim.x + threadIdx.x;
  if (n < NNODES){
    int q  = cursor[n];
    int qe = row_off[n+1];
    for (; q < qe; ++q) csr[q] = NNODES;   // sentinel: its y-row stays zero
  }
}

__global__ void xproj_kernel(const float* __restrict__ x,
                             const float* __restrict__ wr, const float* __restrict__ br,
                             const float* __restrict__ wz, const float* __restrict__ bz,
                             const float* __restrict__ wh, const float* __restrict__ bh,
                             float* __restrict__ xproj){
  int tid = threadIdx.x;             // 0..383
  if (tid >= 384) return;
  int g = tid >> 7; int r = tid & 127; int b = r >> 6; int i = r & 63;
  const float* w  = (g==0)?wr:(g==1)?wz:wh;
  const float* bb = (g==0)?br:(g==1)?bz:bh;
  float s = bb[i];
  for (int k=0;k<INDIM;k++) s = fmaf(x[b*INDIM+k], w[k*HDIM+i], s);
  xproj[g*128 + i*2 + b] = s;
}

__global__ void transpose_w_kernel(const float* __restrict__ gcn_w, float* __restrict__ wT){
  int tid = threadIdx.x;
  for (int k=0;k<16;k++){
    int idx = tid*16 + k;
    int i = idx >> 6, j = idx & 63;       // wT[i][j] = W[j][i]
    wT[idx] = gcn_w[j*HDIM + i];
  }
}

#define ACC8(q0,q1,q2,q3,q4,q5,q6,q7) do{ \
  A0.x += __uint_as_float((q0)<<16); A0.y += __uint_as_float((q0)&0xffff0000u); \
  A1.x += __uint_as_float((q1)<<16); A1.y += __uint_as_float((q1)&0xffff0000u); \
  A2.x += __uint_as_float((q2)<<16); A2.y += __uint_as_float((q2)&0xffff0000u); \
  A3.x += __uint_as_float((q3)<<16); A3.y += __uint_as_float((q3)&0xffff0000u); \
  A0.x += __uint_as_float((q4)<<16); A0.y += __uint_as_float((q4)&0xffff0000u); \
  A1.x += __uint_as_float((q5)<<16); A1.y += __uint_as_float((q5)&0xffff0000u); \
  A2.x += __uint_as_float((q6)<<16); A2.y += __uint_as_float((q6)&0xffff0000u); \
  A3.x += __uint_as_float((q7)<<16); A3.y += __uint_as_float((q7)&0xffff0000u); \
}while(0)

// Persistent cooperative kernel: all 50 steps in one launch.
// Wave owns nodes {wid, wid+6144}; h in registers; W + csr byte-offsets in LDS.
__launch_bounds__(512, 6)
__global__ void fused_kernel(const uint32_t* __restrict__ yb0,
                             uint32_t* __restrict__ yb1,
                             float* __restrict__ out,
                             const int* __restrict__ row_off,
                             const int* __restrict__ csr,
                             const float* __restrict__ norm_d,
                             const float* __restrict__ norm_s,
                             const float* __restrict__ wT,
                             const float* __restrict__ gcn_b,
                             const float2* __restrict__ xproj){
  __shared__ __align__(16) float4   wlds[64][16];    // 16 KB swizzled W
  __shared__ __align__(16) float2   hstage[8][64];   // 4 KB wave-private
  __shared__ __align__(16) uint32_t offlds[8][2][64];// 4 KB csr byte-offsets

  cg::grid_group grid = cg::this_grid();

  const int tid  = threadIdx.x;
  const int lane = tid & 63;
  const int wv   = tid >> 6;

  { // stage W into LDS, swizzled at float4 granularity
    const float4* wt4 = (const float4*)wT;
    #pragma unroll
    for (int q=0;q<2;q++){
      int c = tid*2 + q;
      int l = c >> 4, kk = c & 15;
      int swl = (l & 15) ^ (((l>>4)&1) << 2);
      wlds[l][kk ^ swl] = wt4[c];
    }
  }

  const int wid = blockIdx.x*8 + wv;      // 0..6143
  int nds[2]; nds[0] = wid; nds[1] = wid + GWAVES;
  const bool has1 = (nds[1] < NNODES);

  int   begk[2] = {0,0};
  int   nrk[2]  = {0,0};
  float ndk[2]  = {0.f,0.f}, nsk[2] = {0.f,0.f};

  #pragma unroll
  for (int k=0;k<2;k++){
    if (k==0 || has1){
      int n = nds[k];
      int beg = __builtin_amdgcn_readfirstlane(row_off[n]);
      int end = __builtin_amdgcn_readfirstlane(row_off[n+1]);
      int pdeg = end - beg;                 // multiple of 8
      int cap = pdeg < 64 ? pdeg : 64;
      if (lane < cap) offlds[wv][k][lane] = (uint32_t)csr[beg+lane]*256u;
      begk[k] = beg;
      nrk[k]  = pdeg >> 3;
      ndk[k]  = norm_d[n];
      nsk[k]  = norm_s[n];
    }
  }

  const float  bias = gcn_b[lane];
  const float2 xrv  = xproj[lane];
  const float2 xzv  = xproj[64+lane];
  const float2 xhv  = xproj[128+lane];
  const int    sl   = (lane & 15) ^ (((lane>>4)&1) << 2);

  float2 hreg[2] = {make_float2(0.f,0.f), make_float2(0.f,0.f)};

  __syncthreads();   // wlds ready

  const uint32_t* ybin  = yb0;
  uint32_t*       ybout = yb1;
  const size_t NH = (size_t)NNODES*HDIM;

  #pragma unroll 1
  for (int t=0;t<TSTEPS;t++){
    #pragma unroll
    for (int k=0;k<2;k++){
      if (k==0 || has1){
        const int n = nds[k];
        float2 A0{0.f,0.f},A1{0.f,0.f},A2{0.f,0.f},A3{0.f,0.f};
        const char* ybb = (const char*)ybin + (uint32_t)(lane*4);
        const uint4* op = (const uint4*)offlds[wv][k];
        const int nr  = nrk[k];
        const int nr8 = nr < 8 ? nr : 8;
        int r = 0;
        #pragma unroll 1
        for (; r+2 <= nr8; r+=2){          // 16 gathers in flight
          uint4 oa = op[2*r+0], ob = op[2*r+1];
          uint32_t p0 = *(const uint32_t*)(ybb+oa.x);
          uint32_t p1 = *(const uint32_t*)(ybb+oa.y);
          uint32_t p2 = *(const uint32_t*)(ybb+oa.z);
          uint32_t p3 = *(const uint32_t*)(ybb+oa.w);
          uint32_t p4 = *(const uint32_t*)(ybb+ob.x);
          uint32_t p5 = *(const uint32_t*)(ybb+ob.y);
          uint32_t p6 = *(const uint32_t*)(ybb+ob.z);
          uint32_t p7 = *(const uint32_t*)(ybb+ob.w);
          uint4 oc = op[2*r+2], od = op[2*r+3];
          uint32_t p8  = *(const uint32_t*)(ybb+oc.x);
          uint32_t p9  = *(const uint32_t*)(ybb+oc.y);
          uint32_t p10 = *(const uint32_t*)(ybb+oc.z);
          uint32_t p11 = *(const uint32_t*)(ybb+oc.w);
          uint32_t p12 = *(const uint32_t*)(ybb+od.x);
          uint32_t p13 = *(const uint32_t*)(ybb+od.y);
          uint32_t p14 = *(const uint32_t*)(ybb+od.z);
          uint32_t p15 = *(const uint32_t*)(ybb+od.w);
          ACC8(p0,p1,p2,p3,p4,p5,p6,p7);
          ACC8(p8,p9,p10,p11,p12,p13,p14,p15);
        }
        if (r < nr8){                       // odd 8-group
          uint4 oa = op[2*r], ob = op[2*r+1];
          uint32_t p0 = *(const uint32_t*)(ybb+oa.x);
          uint32_t p1 = *(const uint32_t*)(ybb+oa.y);
          uint32_t p2 = *(const uint32_t*)(ybb+oa.z);
          uint32_t p3 = *(const uint32_t*)(ybb+oa.w);
          uint32_t p4 = *(const uint32_t*)(ybb+ob.x);
          uint32_t p5 = *(const uint32_t*)(ybb+ob.y);
          uint32_t p6 = *(const uint32_t*)(ybb+ob.z);
          uint32_t p7 = *(const uint32_t*)(ybb+ob.w);
          ACC8(p0,p1,p2,p3,p4,p5,p6,p7);
          r++;
        }
        #pragma unroll 1
        for (; r < nr; ++r){                // cold path: deg > 64 (won't trigger here)
          const int4* cq = (const int4*)(csr + begk[k] + 8*r);
          int4 ca = cq[0], cb = cq[1];
          uint32_t p0 = *(const uint32_t*)(ybb+(uint32_t)ca.x*256u);
          uint32_t p1 = *(const uint32_t*)(ybb+(uint32_t)ca.y*256u);
          uint32_t p2 = *(const uint32_t*)(ybb+(uint32_t)ca.z*256u);
          uint32_t p3 = *(const uint32_t*)(ybb+(uint32_t)ca.w*256u);
          uint32_t p4 = *(const uint32_t*)(ybb+(uint32_t)cb.x*256u);
          uint32_t p5 = *(const uint32_t*)(ybb+(uint32_t)cb.y*256u);
          uint32_t p6 = *(const uint32_t*)(ybb+(uint32_t)cb.z*256u);
          uint32_t p7 = *(const uint32_t*)(ybb+(uint32_t)cb.w*256u);
          ACC8(p0,p1,p2,p3,p4,p5,p6,p7);
        }
        float s0 = (A0.x+A1.x)+(A2.x+A3.x);
        float s1 = (A0.y+A1.y)+(A2.y+A3.y);
        float g0 = fmaf(ndk[k], s0, bias);
        float g1 = fmaf(ndk[k], s1, bias);
        float r0 = sigmoidf_(xrv.x+g0), r1 = sigmoidf_(xrv.y+g1);
        float z0 = sigmoidf_(xzv.x+g0), z1 = sigmoidf_(xzv.y+g1);
        float t0 = tanhf_(xhv.x+r0*g0), t1 = tanhf_(xhv.y+r1*g1);
        float hn0 = hreg[k].x + z0*(t0 - hreg[k].x);
        float hn1 = hreg[k].y + z1*(t1 - hreg[k].y);
        hreg[k] = make_float2(hn0,hn1);

        size_t idx = (size_t)t*NH + (size_t)n*HDIM + lane;
        __builtin_nontemporal_store(hn0, &out[idx]);
        __builtin_nontemporal_store(hn1, &out[(size_t)TSTEPS*NH + idx]);

        // y_new = h_new @ W for next step's gather
        hstage[wv][lane] = make_float2(hn0,hn1);
        __asm__ volatile("s_waitcnt lgkmcnt(0)" ::: "memory");  // wave-private slot
        const float4* hp = (const float4*)hstage[wv];
        float y0 = 0.f, y1 = 0.f;
        #pragma unroll
        for (int kk=0;kk<16;kk++){
          float4 w4 = wlds[lane][kk ^ sl];
          float4 ha = hp[2*kk];
          float4 hb = hp[2*kk+1];
          y0 = fmaf(w4.x, ha.x, y0); y1 = fmaf(w4.x, ha.y, y1);
          y0 = fmaf(w4.y, ha.z, y0); y1 = fmaf(w4.y, ha.w, y1);
          y0 = fmaf(w4.z, hb.x, y0); y1 = fmaf(w4.z, hb.y, y1);
          y0 = fmaf(w4.w, hb.z, y0); y1 = fmaf(w4.w, hb.w, y1);
        }
        ybout[(uint32_t)n*HDIM + lane] = pack_bf16x2(nsk[k]*y0, nsk[k]*y1);
      }
    }
    if (t+1 < TSTEPS) grid.sync();     // all threads reach this uniformly
    const uint32_t* tin = ybin; ybin = ybout; ybout = (uint32_t*)tin;
  }
}

// ---------- fallback per-step kernel (round-2 proven path) ----------
__launch_bounds__(512, 6)
__global__ void step_kernel(const float2* __restrict__ h_in, float2* __restrict__ h_out,
                            const uint32_t* __restrict__ yb_in, uint32_t* __restrict__ yb_out,
                            float* __restrict__ out, int t,
                            const int* __restrict__ row_off, const int* __restrict__ csr,
                            const float* __restrict__ norm_d, const float* __restrict__ norm_s,
                            const float* __restrict__ wT, const float* __restrict__ gcn_b,
                            const float2* __restrict__ xproj){
  __shared__ __align__(16) float4 wlds[64][16];
  __shared__ __align__(16) float2 hstage[8][64];

  const int tid  = threadIdx.x;
  const int lane = tid & 63;
  const int wv   = tid >> 6;

  {
    const float4* wt4 = (const float4*)wT;
    #pragma unroll
    for (int q=0;q<2;q++){
      int c = tid*2 + q;
      int l = c >> 4, k = c & 15;
      int swl = (l & 15) ^ (((l>>4)&1) << 2);
      wlds[l][k ^ swl] = wt4[c];
    }
  }

  const int n   = __builtin_amdgcn_readfirstlane(blockIdx.x*8 + wv);
  const int beg = __builtin_amdgcn_readfirstlane(row_off[n]);
  const int end = __builtin_amdgcn_readfirstlane(row_off[n+1]);

  __syncthreads();

  float2 hold = h_in[(size_t)n*HDIM + lane];

  const uint32_t lane_u = (uint32_t)lane;
  float2 A0{0.f,0.f}, A1{0.f,0.f}, A2{0.f,0.f}, A3{0.f,0.f};
  const int4* cp = (const int4*)(csr + beg);
  int nIt = (end - beg) >> 3;
  #pragma unroll 1
  for (int it=0; it<nIt; ++it){
    int4 ca = cp[2*it];
    int4 cb = cp[2*it+1];
    uint32_t p0 = yb_in[(uint32_t)ca.x*HDIM + lane_u];
    uint32_t p1 = yb_in[(uint32_t)ca.y*HDIM + lane_u];
    uint32_t p2 = yb_in[(uint32_t)ca.z*HDIM + lane_u];
    uint32_t p3 = yb_in[(uint32_t)ca.w*HDIM + lane_u];
    uint32_t p4 = yb_in[(uint32_t)cb.x*HDIM + lane_u];
    uint32_t p5 = yb_in[(uint32_t)cb.y*HDIM + lane_u];
    uint32_t p6 = yb_in[(uint32_t)cb.z*HDIM + lane_u];
    uint32_t p7 = yb_in[(uint32_t)cb.w*HDIM + lane_u];
    ACC8(p0,p1,p2,p3,p4,p5,p6,p7);
  }
  float s0 = (A0.x + A1.x) + (A2.x + A3.x);
  float s1 = (A0.y + A1.y) + (A2.y + A3.y);

  const float nd   = norm_d[n];
  const float ns   = norm_s[n];
  const float bias = gcn_b[lane];
  const float2 xrv = xproj[lane];
  const float2 xzv = xproj[64+lane];
  const float2 xhv = xproj[128+lane];

  float g0 = fmaf(nd, s0, bias);
  float g1 = fmaf(nd, s1, bias);

  float r0 = sigmoidf_(xrv.x + g0), r1 = sigmoidf_(xrv.y + g1);
  float z0 = sigmoidf_(xzv.x + g0), z1 = sigmoidf_(xzv.y + g1);
  float t0 = tanhf_(xhv.x + r0*g0), t1 = tanhf_(xhv.y + r1*g1);
  float hn0 = hold.x + z0*(t0 - hold.x);
  float hn1 = hold.y + z1*(t1 - hold.y);

  const size_t NH = (size_t)NNODES*HDIM;
  h_out[(size_t)n*HDIM + lane] = make_float2(hn0,hn1);
  size_t idx = (size_t)t*NH + (size_t)n*HDIM + lane;
  __builtin_nontemporal_store(hn0, &out[idx]);
  __builtin_nontemporal_store(hn1, &out[(size_t)TSTEPS*NH + idx]);

  hstage[wv][lane] = make_float2(hn0,hn1);
  __asm__ volatile("s_waitcnt lgkmcnt(0)" ::: "memory");

  const int sl = (lane & 15) ^ (((lane>>4)&1) << 2);
  const float4* hp = (const float4*)hstage[wv];
  float y0 = 0.f, y1 = 0.f;
  #pragma unroll
  for (int k=0;k<16;k++){
    float4 w4 = wlds[lane][k ^ sl];
    float4 ha = hp[2*k];
    float4 hb = hp[2*k+1];
    y0 = fmaf(w4.x, ha.x, y0); y1 = fmaf(w4.x, ha.y, y1);
    y0 = fmaf(w4.y, ha.z, y0); y1 = fmaf(w4.y, ha.w, y1);
    y0 = fmaf(w4.z, hb.x, y0); y1 = fmaf(w4.z, hb.y, y1);
    y0 = fmaf(w4.w, hb.z, y0); y1 = fmaf(w4.w, hb.w, y1);
  }
  yb_out[(size_t)n*HDIM + lane] = pack_bf16x2(ns*y0, ns*y1);
}

extern "C" void kernel_launch(void* const* d_in, const int* in_sizes, int n_in,
                              void* d_out, int out_size, void* d_ws, size_t ws_size,
                              hipStream_t stream){
  const float* x   = (const float*)d_in[0];
  const int*   src = (const int*)d_in[1];
  const int*   dst = (const int*)d_in[2];
  const float* wr  = (const float*)d_in[3];
  const float* br  = (const float*)d_in[4];
  const float* wz  = (const float*)d_in[5];
  const float* bz  = (const float*)d_in[6];
  const float* wh  = (const float*)d_in[7];
  const float* bh  = (const float*)d_in[8];
  const float* gw  = (const float*)d_in[9];
  const float* gb  = (const float*)d_in[10];
  float* out = (float*)d_out;
  const int E = in_sizes[1];

  char* ws = (char*)d_ws;
  size_t o = 0;
  int*   deg_out = (int*)(ws+o);  o += 10240*4;
  int*   deg_in  = (int*)(ws+o);  o += 10240*4;
  int*   cursor  = (int*)(ws+o);  o += 10240*4;
  int*   row_off = (int*)(ws+o);  o += 10256*4;
  float* norm_s  = (float*)(ws+o); o += 10240*4;
  float* norm_d  = (float*)(ws+o); o += 10240*4;
  const size_t CSRCAP = (size_t)E + 7*NNODES + 16;
  int*   csr     = (int*)(ws+o);  o += ((CSRCAP*4 + 15) & ~(size_t)15);
  float* xproj   = (float*)(ws+o); o += 512*4;
  float* wT      = (float*)(ws+o); o += 4096*4;
  o = (o + 255) & ~(size_t)255;
  const size_t NHf2 = (size_t)NNODES*HDIM*sizeof(float2);        // 5.12 MB
  const size_t NYB  = (size_t)(NNODES+1)*HDIM*sizeof(uint32_t);  // 2.56 MB (+sentinel)
  uint32_t* yb0 = (uint32_t*)(ws+o); o += NYB;   // contiguous pair -> one memset
  uint32_t* yb1 = (uint32_t*)(ws+o); o += NYB;
  float2*   h0  = (float2*)(ws+o);   o += NHf2;  // fallback only
  float2*   h1  = (float2*)(ws+o);   o += NHf2;

  hipMemsetAsync(deg_out, 0, 2*10240*4, stream);
  hipMemsetAsync(yb0, 0, 2*NYB, stream);   // zeros yb0 and yb1 (sentinel rows too)

  int eb = (E+255)/256;
  hist_kernel<<<eb,256,0,stream>>>(src,dst,deg_out,deg_in,E);
  scan_kernel<<<1,256,0,stream>>>(deg_in,deg_out,row_off,cursor,norm_s,norm_d);
  fill_kernel<<<eb,256,0,stream>>>(src,dst,cursor,csr,E);
  pad_kernel<<<(NNODES+255)/256,256,0,stream>>>(row_off,cursor,csr);
  xproj_kernel<<<1,384,0,stream>>>(x,wr,br,wz,bz,wh,bh,xproj);
  transpose_w_kernel<<<1,256,0,stream>>>(gw,wT);

  // cooperative fused path
  const uint32_t* a_yb0 = yb0;
  uint32_t*       a_yb1 = yb1;
  float*          a_out = out;
  const int*      a_ro  = row_off;
  const int*      a_csr = csr;
  const float*    a_nd  = norm_d;
  const float*    a_ns  = norm_s;
  const float*    a_wT  = wT;
  const float*    a_gb  = gb;
  const float2*   a_xp  = (const float2*)xproj;
  void* kparams[10] = { (void*)&a_yb0, (void*)&a_yb1, (void*)&a_out, (void*)&a_ro,
                        (void*)&a_csr, (void*)&a_nd, (void*)&a_ns, (void*)&a_wT,
                        (void*)&a_gb, (void*)&a_xp };
  hipError_t ce = hipLaunchCooperativeKernel((const void*)fused_kernel,
                                             dim3(GBLK), dim3(512), kparams, 0, stream);
  if (ce != hipSuccess){
    (void)hipGetLastError();            // clear sticky error, take fallback path
    hipMemsetAsync(h0, 0, NHf2, stream);
    float2* hin = h0;  float2* hout = h1;
    uint32_t* ybin = yb0; uint32_t* ybout = yb1;
    for (int t=0;t<TSTEPS;t++){
      step_kernel<<<1250,512,0,stream>>>(hin,hout,ybin,ybout,out,t,row_off,csr,
                                         norm_d,norm_s,wT,gb,(const float2*)xproj);
      float2* tf = hin; hin = hout; hout = tf;
      uint32_t* tb = ybin; ybin = ybout; ybout = tb;
    }
  }
}

// Round 4
// 989.508 us; speedup vs baseline: 5.0183x; 5.0183x over previous
//
#include <hip/hip_runtime.h>
#include <cstdint>
#include <cstddef>

#define NNODES 10000
#define HDIM 64
#define INDIM 128
#define TSTEPS 50

__device__ __forceinline__ float sigmoidf_(float x){ return 1.0f/(1.0f+__expf(-x)); }
__device__ __forceinline__ float tanhf_(float x){ float e=__expf(2.0f*x); return 1.0f-2.0f/(e+1.0f); }

__device__ __forceinline__ uint32_t pack_bf16x2(float a, float b){
  uint32_t ua = __float_as_uint(a), ub = __float_as_uint(b);
  ua = (ua + 0x7fffu + ((ua>>16)&1u)) >> 16;          // rne
  ub = (ub + 0x7fffu + ((ub>>16)&1u)) >> 16;
  return ua | (ub<<16);
}

__global__ void hist_kernel(const int* __restrict__ src, const int* __restrict__ dst,
                            int* __restrict__ deg_out, int* __restrict__ deg_in, int E){
  int e = blockIdx.x*blockDim.x + threadIdx.x;
  if (e < E){
    atomicAdd(&deg_out[src[e]], 1);
    atomicAdd(&deg_in[dst[e]], 1);
  }
}

// row_off uses degrees PADDED to multiples of 8 (branch-free 8-unroll gather)
__global__ void scan_kernel(const int* __restrict__ deg_in, const int* __restrict__ deg_out,
                            int* __restrict__ row_off, int* __restrict__ cursor,
                            float* __restrict__ norm_s, float* __restrict__ norm_d){
  __shared__ int part[256];
  int tid = threadIdx.x;
  const int CH = (NNODES + 255)/256;   // 40
  int base = tid*CH;
  int local = 0;
  for (int k=0;k<CH;k++){ int n=base+k; if(n<NNODES) local += (deg_in[n]+7)&~7; }
  part[tid]=local;
  __syncthreads();
  if (tid==0){
    int run=0;
    for(int i=0;i<256;i++){ int t=part[i]; part[i]=run; run+=t; }
  }
  __syncthreads();
  int run = part[tid];
  for (int k=0;k<CH;k++){
    int n=base+k;
    if (n<NNODES){
      int di = deg_in[n];
      row_off[n]=run; cursor[n]=run;
      run += (di+7)&~7;
      norm_d[n] = rsqrtf(fmaxf((float)di,1.0f));
      norm_s[n] = rsqrtf(fmaxf((float)deg_out[n],1.0f));
    }
  }
  if (tid==255) row_off[NNODES]=run;   // padded E
}

// csr stores BYTE offsets into the yb table (src*256); sentinel row NNODES stays zero
__global__ void fill_kernel(const int* __restrict__ src, const int* __restrict__ dst,
                            int* __restrict__ cursor, uint32_t* __restrict__ csrb, int E){
  int e = blockIdx.x*blockDim.x + threadIdx.x;
  if (e<E){
    int pos = atomicAdd(&cursor[dst[e]],1);
    csrb[pos] = (uint32_t)src[e]*256u;
  }
}

__global__ void pad_kernel(const int* __restrict__ row_off, const int* __restrict__ cursor,
                           uint32_t* __restrict__ csrb){
  int n = blockIdx.x*blockDim.x + threadIdx.x;
  if (n < NNODES){
    int q  = cursor[n];
    int qe = row_off[n+1];
    for (; q < qe; ++q) csrb[q] = (uint32_t)NNODES*256u;   // zero sentinel row
  }
}

__global__ void xproj_kernel(const float* __restrict__ x,
                             const float* __restrict__ wr, const float* __restrict__ br,
                             const float* __restrict__ wz, const float* __restrict__ bz,
                             const float* __restrict__ wh, const float* __restrict__ bh,
                             float* __restrict__ xproj){
  int tid = threadIdx.x;             // 0..383
  if (tid >= 384) return;
  int g = tid >> 7; int r = tid & 127; int b = r >> 6; int i = r & 63;
  const float* w  = (g==0)?wr:(g==1)?wz:wh;
  const float* bb = (g==0)?br:(g==1)?bz:bh;
  float s = bb[i];
  for (int k=0;k<INDIM;k++) s = fmaf(x[b*INDIM+k], w[k*HDIM+i], s);
  xproj[g*128 + i*2 + b] = s;
}

__global__ void transpose_w_kernel(const float* __restrict__ gcn_w, float* __restrict__ wT){
  int tid = threadIdx.x;
  for (int k=0;k<16;k++){
    int idx = tid*16 + k;
    int i = idx >> 6, j = idx & 63;       // wT[i][j] = W[j][i]
    wT[idx] = gcn_w[j*HDIM + i];
  }
}

#define ACC8(A0,A1,A2,A3,q0,q1,q2,q3,q4,q5,q6,q7) do{ \
  A0.x += __uint_as_float((q0)<<16); A0.y += __uint_as_float((q0)&0xffff0000u); \
  A1.x += __uint_as_float((q1)<<16); A1.y += __uint_as_float((q1)&0xffff0000u); \
  A2.x += __uint_as_float((q2)<<16); A2.y += __uint_as_float((q2)&0xffff0000u); \
  A3.x += __uint_as_float((q3)<<16); A3.y += __uint_as_float((q3)&0xffff0000u); \
  A0.x += __uint_as_float((q4)<<16); A0.y += __uint_as_float((q4)&0xffff0000u); \
  A1.x += __uint_as_float((q5)<<16); A1.y += __uint_as_float((q5)&0xffff0000u); \
  A2.x += __uint_as_float((q6)<<16); A2.y += __uint_as_float((q6)&0xffff0000u); \
  A3.x += __uint_as_float((q7)<<16); A3.y += __uint_as_float((q7)&0xffff0000u); \
}while(0)

#define GATHER8(cp,it,P0,P1,P2,P3,P4,P5,P6,P7) \
  uint4 oa##P0 = (cp)[2*(it)], ob##P0 = (cp)[2*(it)+1]; \
  uint32_t P0 = *(const uint32_t*)(ybb+oa##P0.x); \
  uint32_t P1 = *(const uint32_t*)(ybb+oa##P0.y); \
  uint32_t P2 = *(const uint32_t*)(ybb+oa##P0.z); \
  uint32_t P3 = *(const uint32_t*)(ybb+oa##P0.w); \
  uint32_t P4 = *(const uint32_t*)(ybb+ob##P0.x); \
  uint32_t P5 = *(const uint32_t*)(ybb+ob##P0.y); \
  uint32_t P6 = *(const uint32_t*)(ybb+ob##P0.z); \
  uint32_t P7 = *(const uint32_t*)(ybb+ob##P0.w);

// One wave handles nodes {wid, wid+5000}. 625 blocks -> ALL blocks resident (3/CU).
// Barrier deferred until the y=hW matmul; gathers start immediately.
__launch_bounds__(512, 6)
__global__ void step_kernel(const float2* __restrict__ h_in, float2* __restrict__ h_out,
                            const uint32_t* __restrict__ yb_in, uint32_t* __restrict__ yb_out,
                            float* __restrict__ out, int t,
                            const int* __restrict__ row_off, const uint32_t* __restrict__ csrb,
                            const float* __restrict__ norm_d, const float* __restrict__ norm_s,
                            const float* __restrict__ wT, const float* __restrict__ gcn_b,
                            const float2* __restrict__ xproj){
  __shared__ __align__(16) float4 wlds[64][16];      // 16 KB swizzled W
  __shared__ __align__(16) float2 hstage[8][2][64];  // 8 KB wave-private

  const int tid  = threadIdx.x;
  const int lane = tid & 63;
  const int wv   = tid >> 6;

  // stage W into LDS (ds_writes only; the barrier comes after the gather phase)
  {
    const float4* wt4 = (const float4*)wT;
    #pragma unroll
    for (int q=0;q<2;q++){
      int c = tid*2 + q;
      int l = c >> 4, kk = c & 15;
      int swl = (l & 15) ^ (((l>>4)&1) << 2);
      wlds[l][kk ^ swl] = wt4[c];
    }
  }

  const int wid = __builtin_amdgcn_readfirstlane(blockIdx.x*8 + wv);  // 0..4999
  const int n0 = wid, n1 = wid + 5000;

  int beg0 = __builtin_amdgcn_readfirstlane(row_off[n0]);
  int end0 = __builtin_amdgcn_readfirstlane(row_off[n0+1]);
  int beg1 = __builtin_amdgcn_readfirstlane(row_off[n1]);
  int end1 = __builtin_amdgcn_readfirstlane(row_off[n1+1]);

  float2 hold0 = h_in[(size_t)n0*HDIM + lane];
  float2 hold1 = h_in[(size_t)n1*HDIM + lane];

  const char* ybb = (const char*)yb_in + (uint32_t)(lane*4);
  const uint4* cp0 = (const uint4*)(csrb + beg0);    // beg%8==0 -> 16B aligned
  const uint4* cp1 = (const uint4*)(csrb + beg1);
  const int it0 = (end0-beg0)>>3;
  const int it1 = (end1-beg1)>>3;
  const int itc = it0 < it1 ? it0 : it1;

  float2 A0{0.f,0.f},A1{0.f,0.f},A2{0.f,0.f},A3{0.f,0.f};   // node0
  float2 B0{0.f,0.f},B1{0.f,0.f},B2{0.f,0.f},B3{0.f,0.f};   // node1

  int it = 0;
  #pragma unroll 1
  for (; it<itc; ++it){            // common loop: 16 gathers in flight
    GATHER8(cp0,it,p0,p1,p2,p3,p4,p5,p6,p7);
    GATHER8(cp1,it,q0,q1,q2,q3,q4,q5,q6,q7);
    ACC8(A0,A1,A2,A3,p0,p1,p2,p3,p4,p5,p6,p7);
    ACC8(B0,B1,B2,B3,q0,q1,q2,q3,q4,q5,q6,q7);
  }
  #pragma unroll 1
  for (int ia=it; ia<it0; ++ia){   // node0 tail
    GATHER8(cp0,ia,p0,p1,p2,p3,p4,p5,p6,p7);
    ACC8(A0,A1,A2,A3,p0,p1,p2,p3,p4,p5,p6,p7);
  }
  #pragma unroll 1
  for (int ib=it; ib<it1; ++ib){   // node1 tail
    GATHER8(cp1,ib,q0,q1,q2,q3,q4,q5,q6,q7);
    ACC8(B0,B1,B2,B3,q0,q1,q2,q3,q4,q5,q6,q7);
  }

  float s00 = (A0.x+A1.x)+(A2.x+A3.x), s01 = (A0.y+A1.y)+(A2.y+A3.y);
  float s10 = (B0.x+B1.x)+(B2.x+B3.x), s11 = (B0.y+B1.y)+(B2.y+B3.y);

  const float  bias = gcn_b[lane];
  const float2 xrv  = xproj[lane];
  const float2 xzv  = xproj[64+lane];
  const float2 xhv  = xproj[128+lane];
  const float  nd0  = norm_d[n0], ns0 = norm_s[n0];
  const float  nd1  = norm_d[n1], ns1 = norm_s[n1];

  float g00 = fmaf(nd0, s00, bias), g01 = fmaf(nd0, s01, bias);
  float g10 = fmaf(nd1, s10, bias), g11 = fmaf(nd1, s11, bias);

  float r00 = sigmoidf_(xrv.x+g00), r01 = sigmoidf_(xrv.y+g01);
  float r10 = sigmoidf_(xrv.x+g10), r11 = sigmoidf_(xrv.y+g11);
  float z00 = sigmoidf_(xzv.x+g00), z01 = sigmoidf_(xzv.y+g01);
  float z10 = sigmoidf_(xzv.x+g10), z11 = sigmoidf_(xzv.y+g11);
  float t00 = tanhf_(xhv.x+r00*g00), t01 = tanhf_(xhv.y+r01*g01);
  float t10 = tanhf_(xhv.x+r10*g10), t11 = tanhf_(xhv.y+r11*g11);
  float h00 = hold0.x + z00*(t00 - hold0.x);
  float h01 = hold0.y + z01*(t01 - hold0.y);
  float h10 = hold1.x + z10*(t10 - hold1.x);
  float h11 = hold1.y + z11*(t11 - hold1.y);

  const size_t NH = (size_t)NNODES*HDIM;
  h_out[(size_t)n0*HDIM + lane] = make_float2(h00,h01);
  h_out[(size_t)n1*HDIM + lane] = make_float2(h10,h11);
  size_t idx0 = (size_t)t*NH + (size_t)n0*HDIM + lane;
  size_t idx1 = (size_t)t*NH + (size_t)n1*HDIM + lane;
  __builtin_nontemporal_store(h00, &out[idx0]);
  __builtin_nontemporal_store(h01, &out[(size_t)TSTEPS*NH + idx0]);
  __builtin_nontemporal_store(h10, &out[idx1]);
  __builtin_nontemporal_store(h11, &out[(size_t)TSTEPS*NH + idx1]);

  hstage[wv][0][lane] = make_float2(h00,h01);
  hstage[wv][1][lane] = make_float2(h10,h11);
  __syncthreads();   // wlds ready (and our hstage writes drained)

  // y_new = h_new @ W for both nodes (dual chains, broadcast h + per-lane W column)
  const int sl = (lane & 15) ^ (((lane>>4)&1) << 2);
  const float4* hp0 = (const float4*)hstage[wv][0];
  const float4* hp1 = (const float4*)hstage[wv][1];
  float y00=0.f, y01=0.f, y10=0.f, y11=0.f;
  #pragma unroll
  for (int kk=0;kk<16;kk++){
    float4 w4  = wlds[lane][kk ^ sl];
    float4 ha0 = hp0[2*kk], hb0 = hp0[2*kk+1];
    float4 ha1 = hp1[2*kk], hb1 = hp1[2*kk+1];
    y00 = fmaf(w4.x, ha0.x, y00); y01 = fmaf(w4.x, ha0.y, y01);
    y10 = fmaf(w4.x, ha1.x, y10); y11 = fmaf(w4.x, ha1.y, y11);
    y00 = fmaf(w4.y, ha0.z, y00); y01 = fmaf(w4.y, ha0.w, y01);
    y10 = fmaf(w4.y, ha1.z, y10); y11 = fmaf(w4.y, ha1.w, y11);
    y00 = fmaf(w4.z, hb0.x, y00); y01 = fmaf(w4.z, hb0.y, y01);
    y10 = fmaf(w4.z, hb1.x, y10); y11 = fmaf(w4.z, hb1.y, y11);
    y00 = fmaf(w4.w, hb0.z, y00); y01 = fmaf(w4.w, hb0.w, y01);
    y10 = fmaf(w4.w, hb1.z, y10); y11 = fmaf(w4.w, hb1.w, y11);
  }
  yb_out[(uint32_t)n0*HDIM + lane] = pack_bf16x2(ns0*y00, ns0*y01);
  yb_out[(uint32_t)n1*HDIM + lane] = pack_bf16x2(ns1*y10, ns1*y11);
}

extern "C" void kernel_launch(void* const* d_in, const int* in_sizes, int n_in,
                              void* d_out, int out_size, void* d_ws, size_t ws_size,
                              hipStream_t stream){
  const float* x   = (const float*)d_in[0];
  const int*   src = (const int*)d_in[1];
  const int*   dst = (const int*)d_in[2];
  const float* wr  = (const float*)d_in[3];
  const float* br  = (const float*)d_in[4];
  const float* wz  = (const float*)d_in[5];
  const float* bz  = (const float*)d_in[6];
  const float* wh  = (const float*)d_in[7];
  const float* bh  = (const float*)d_in[8];
  const float* gw  = (const float*)d_in[9];
  const float* gb  = (const float*)d_in[10];
  float* out = (float*)d_out;
  const int E = in_sizes[1];

  char* ws = (char*)d_ws;
  size_t o = 0;
  int*   deg_out = (int*)(ws+o);  o += 10240*4;
  int*   deg_in  = (int*)(ws+o);  o += 10240*4;
  int*   cursor  = (int*)(ws+o);  o += 10240*4;
  int*   row_off = (int*)(ws+o);  o += 10256*4;
  float* norm_s  = (float*)(ws+o); o += 10240*4;
  float* norm_d  = (float*)(ws+o); o += 10240*4;
  const size_t CSRCAP = (size_t)E + 7*NNODES + 16;
  uint32_t* csrb = (uint32_t*)(ws+o);  o += ((CSRCAP*4 + 15) & ~(size_t)15);
  float* xproj   = (float*)(ws+o); o += 512*4;
  float* wT      = (float*)(ws+o); o += 4096*4;
  o = (o + 255) & ~(size_t)255;
  const size_t NHf2 = (size_t)NNODES*HDIM*sizeof(float2);        // 5.12 MB
  const size_t NYB  = (size_t)(NNODES+1)*HDIM*sizeof(uint32_t);  // 2.56 MB (+sentinel)
  uint32_t* yb0 = (uint32_t*)(ws+o); o += NYB;   // yb0,yb1,h0 contiguous -> one memset
  uint32_t* yb1 = (uint32_t*)(ws+o); o += NYB;
  float2*   h0  = (float2*)(ws+o);   o += NHf2;
  float2*   h1  = (float2*)(ws+o);   o += NHf2;  // fully written before first read

  hipMemsetAsync(deg_out, 0, 2*10240*4, stream);
  hipMemsetAsync(yb0, 0, 2*NYB + NHf2, stream);  // zeros yb0, yb1 (sentinels), h0

  int eb = (E+255)/256;
  hist_kernel<<<eb,256,0,stream>>>(src,dst,deg_out,deg_in,E);
  scan_kernel<<<1,256,0,stream>>>(deg_in,deg_out,row_off,cursor,norm_s,norm_d);
  fill_kernel<<<eb,256,0,stream>>>(src,dst,cursor,csrb,E);
  pad_kernel<<<(NNODES+255)/256,256,0,stream>>>(row_off,cursor,csrb);
  xproj_kernel<<<1,384,0,stream>>>(x,wr,br,wz,bz,wh,bh,xproj);
  transpose_w_kernel<<<1,256,0,stream>>>(gw,wT);

  float2* hin = h0;  float2* hout = h1;
  uint32_t* ybin = yb0; uint32_t* ybout = yb1;
  for (int t=0;t<TSTEPS;t++){
    step_kernel<<<625,512,0,stream>>>(hin,hout,ybin,ybout,out,t,row_off,csrb,
                                      norm_d,norm_s,wT,gb,(const float2*)xproj);
    float2* tf = hin; hin = hout; hout = tf;
    uint32_t* tb = ybin; ybin = ybout; ybout = tb;
  }
}